// Round 2
// baseline (992.636 us; speedup 1.0000x reference)
//
#include <hip/hip_runtime.h>
#include <hip/hip_bf16.h>

#define DEV __device__ __forceinline__

DEV float bf2f(__hip_bfloat16 v) { return __bfloat162float(v); }
DEV float lrelu(float x) { return x > 0.f ? x : 0.2f * x; }
DEV float eluf(float x) { return x > 0.f ? x : (__expf(x) - 1.f); }

// Read element i of a float tensor that is either bf16 (f=1) or fp32 (f=0).
DEV float ldf(const void* p, int i, int f) {
    return f ? bf2f(((const __hip_bfloat16*)p)[i]) : ((const float*)p)[i];
}

// ---------------- dtype detection ----------------
// If data is bf16: low 16 bits of each 32-bit word are a bf16 of ~N(0,1)
// -> exponent field in [112,130] with prob ~0.999.
// If data is fp32: low 16 bits are uniform mantissa bits -> prob ~0.074.

__global__ void k_detect(const unsigned int* __restrict__ w, int* __restrict__ flag) {
    int t = threadIdx.x;  // 64 threads
    int cnt = 0;
    for (int i = t; i < 256; i += 64) {
        unsigned int e = (w[i] >> 7) & 0xFFu;
        if (e >= 112u && e <= 130u) cnt++;
    }
    #pragma unroll
    for (int off = 32; off; off >>= 1) cnt += __shfl_xor(cnt, off);
    if (t == 0) *flag = (cnt > 128) ? 1 : 0;
}

// ---------------- param conversion (all small tensors -> fp32 P buffer) ----------------

struct Ptrs14 { const void* p[14]; };

// offsets into P:
#define P_W0 0
#define P_W1 4096
#define P_W2 12288
#define P_AS0 14336
#define P_AD0 14400
#define P_B0 14464
#define P_AS1 14528
#define P_AD1 14592
#define P_B1 14656
#define P_AS2 14720
#define P_AD2 14736
#define P_B2 14752
#define P_GAMMA 14768
#define P_BETA 14784
#define P_TOTAL 14800

__global__ void k_params(Ptrs14 pp, const int* __restrict__ flag, float* __restrict__ P) {
    const int narr[14]  = {4096, 8192, 2048, 64, 64, 64, 64, 64, 64, 16, 16, 16, 16, 16};
    const int oarr[14]  = {P_W0, P_W1, P_W2, P_AS0, P_AD0, P_B0, P_AS1, P_AD1, P_B1,
                           P_AS2, P_AD2, P_B2, P_GAMMA, P_BETA};
    int b = blockIdx.x;
    int f = *flag;
    const void* src = pp.p[b];
    int nn = narr[b], oo = oarr[b];
    for (int i = threadIdx.x; i < nn; i += blockDim.x)
        P[oo + i] = ldf(src, i, f);
}

// ---------------- CSR build (dst-bucketed, no prefix scan) ----------------

__global__ void k_deg(const int* __restrict__ dst, int E, int* __restrict__ deg) {
    int i = blockIdx.x * blockDim.x + threadIdx.x;
    if (i < E) atomicAdd(&deg[dst[i]], 1);
}

__global__ void k_alloc(const int* __restrict__ deg, int* __restrict__ rowptr,
                        int* __restrict__ counter, int N) {
    int i = blockIdx.x * blockDim.x + threadIdx.x;
    if (i < N) rowptr[i] = atomicAdd(counter, deg[i]);
}

__global__ void k_fill(const int* __restrict__ src, const int* __restrict__ dst, int E,
                       const int* __restrict__ rowptr, int* __restrict__ fill,
                       int* __restrict__ col) {
    int i = blockIdx.x * blockDim.x + threadIdx.x;
    if (i < E) {
        int d = dst[i];
        int p = rowptr[d] + atomicAdd(&fill[d], 1);
        col[p] = src[i];
    }
}

// ---------------- GEMM K=64 -> 64 cols, fused a_src/a_dst dots ----------------

__global__ __launch_bounds__(256) void k_gemm_k64(
    const void* __restrict__ X, const int* __restrict__ flag,
    const float* __restrict__ W, const float* __restrict__ av64,
    const float* __restrict__ dv64,
    float* __restrict__ Hout, float* __restrict__ as_, float* __restrict__ ad_, int N)
{
    __shared__ float Ws[64 * 64];
    __shared__ float xs[16 * 64];
    int t = threadIdx.x;
    int f = *flag;
    int rowBase = blockIdx.x * 16;
    for (int idx = t; idx < 64 * 64; idx += 256) Ws[idx] = W[idx];
    for (int idx = t; idx < 16 * 64; idx += 256) {
        int rr = idx >> 6, k = idx & 63;
        int row = rowBase + rr;
        xs[idx] = (row < N) ? ldf(X, row * 64 + k, f) : 0.f;
    }
    __syncthreads();
    int c = t & 63, rg = t >> 6;
    float acc[4] = {0.f, 0.f, 0.f, 0.f};
    #pragma unroll 8
    for (int k = 0; k < 64; k++) {
        float wv = Ws[k * 64 + c];
        #pragma unroll
        for (int rr = 0; rr < 4; rr++) acc[rr] += xs[(rg * 4 + rr) * 64 + k] * wv;
    }
    float av = av64[c], dv = dv64[c];
    #pragma unroll
    for (int rr = 0; rr < 4; rr++) {
        int row = rowBase + rg * 4 + rr;
        float vs = acc[rr] * av, vd = acc[rr] * dv;
        #pragma unroll
        for (int off = 32; off; off >>= 1) {
            vs += __shfl_xor(vs, off);
            vd += __shfl_xor(vd, off);
        }
        if (row < N) {
            Hout[row * 64 + c] = acc[rr];
            if (c == 0) { as_[row] = vs; ad_[row] = vd; }
        }
    }
}

// ---------------- GEMM K=128 (A = [fp32 ws | raw input]) -> 64 cols ----------------

__global__ __launch_bounds__(256) void k_gemm_k128(
    const float* __restrict__ A1, const void* __restrict__ A2,
    const int* __restrict__ flag, const float* __restrict__ W,
    const float* __restrict__ av64, const float* __restrict__ dv64,
    float* __restrict__ Hout, float* __restrict__ as_, float* __restrict__ ad_, int N)
{
    __shared__ float Ws[128 * 64];   // 32 KB
    __shared__ float xs[16 * 128];   // 8 KB
    int t = threadIdx.x;
    int f = *flag;
    int rowBase = blockIdx.x * 16;
    for (int idx = t; idx < 128 * 64; idx += 256) Ws[idx] = W[idx];
    for (int idx = t; idx < 16 * 128; idx += 256) {
        int rr = idx >> 7, k = idx & 127;
        int row = rowBase + rr;
        float v = 0.f;
        if (row < N) v = (k < 64) ? A1[row * 64 + k] : ldf(A2, row * 64 + (k - 64), f);
        xs[idx] = v;
    }
    __syncthreads();
    int c = t & 63, rg = t >> 6;
    float acc[4] = {0.f, 0.f, 0.f, 0.f};
    #pragma unroll 8
    for (int k = 0; k < 128; k++) {
        float wv = Ws[k * 64 + c];
        #pragma unroll
        for (int rr = 0; rr < 4; rr++) acc[rr] += xs[(rg * 4 + rr) * 128 + k] * wv;
    }
    float av = av64[c], dv = dv64[c];
    #pragma unroll
    for (int rr = 0; rr < 4; rr++) {
        int row = rowBase + rg * 4 + rr;
        float vs = acc[rr] * av, vd = acc[rr] * dv;
        #pragma unroll
        for (int off = 32; off; off >>= 1) {
            vs += __shfl_xor(vs, off);
            vd += __shfl_xor(vd, off);
        }
        if (row < N) {
            Hout[row * 64 + c] = acc[rr];
            if (c == 0) { as_[row] = vs; ad_[row] = vd; }
        }
    }
}

// ---------------- GEMM K=128 (A = [fp32 | fp32]) -> 16 cols ----------------

#define XS_STRIDE 129

__global__ __launch_bounds__(256) void k_gemm_k128_c16(
    const float* __restrict__ A1, const float* __restrict__ A2,
    const float* __restrict__ W, const float* __restrict__ av16,
    const float* __restrict__ dv16,
    float* __restrict__ Hout, float* __restrict__ as_, float* __restrict__ ad_, int N)
{
    __shared__ float Ws[128 * 16];          // 8 KB
    __shared__ float xs[64 * XS_STRIDE];    // ~33 KB
    int t = threadIdx.x;
    int rowBase = blockIdx.x * 64;
    for (int idx = t; idx < 128 * 16; idx += 256) Ws[idx] = W[idx];
    for (int idx = t; idx < 64 * 128; idx += 256) {
        int rr = idx >> 7, k = idx & 127;
        int row = rowBase + rr;
        float v = 0.f;
        if (row < N) v = (k < 64) ? A1[row * 64 + k] : A2[row * 64 + (k - 64)];
        xs[rr * XS_STRIDE + k] = v;
    }
    __syncthreads();
    int c = t & 15, g = t >> 4;
    float acc[4] = {0.f, 0.f, 0.f, 0.f};
    #pragma unroll 8
    for (int k = 0; k < 128; k++) {
        float wv = Ws[k * 16 + c];
        #pragma unroll
        for (int rr = 0; rr < 4; rr++) acc[rr] += xs[(g * 4 + rr) * XS_STRIDE + k] * wv;
    }
    float av = av16[c], dv = dv16[c];
    #pragma unroll
    for (int rr = 0; rr < 4; rr++) {
        int row = rowBase + g * 4 + rr;
        float vs = acc[rr] * av, vd = acc[rr] * dv;
        #pragma unroll
        for (int off = 8; off; off >>= 1) {
            vs += __shfl_xor(vs, off);
            vd += __shfl_xor(vd, off);
        }
        if (row < N) {
            Hout[row * 16 + c] = acc[rr];
            if (c == 0) { as_[row] = vs; ad_[row] = vd; }
        }
    }
}

// ---------------- Aggregation F=64: one wave per node ----------------

__global__ __launch_bounds__(256) void k_agg64(
    const int* __restrict__ rowptr, const int* __restrict__ deg,
    const int* __restrict__ col, const float* __restrict__ as_,
    const float* __restrict__ ad_, const float* __restrict__ h,
    const float* __restrict__ bias, float* __restrict__ out,
    int N, int doElu)
{
    int wid = (blockIdx.x * blockDim.x + threadIdx.x) >> 6;
    int lane = threadIdx.x & 63;
    if (wid >= N) return;
    int start = rowptr[wid];
    int d = deg[wid];
    float adi = ad_[wid];
    float asi = as_[wid];
    float eself = lrelu(asi + adi);

    // pass A: segment max (self loop included via init)
    float m = eself;
    for (int j = lane; j < d; j += 64) {
        int s = col[start + j];
        m = fmaxf(m, lrelu(as_[s] + adi));
    }
    #pragma unroll
    for (int off = 32; off; off >>= 1) m = fmaxf(m, __shfl_xor(m, off));

    // pass B: sum of exp
    float ssum = (lane == 0) ? __expf(eself - m) : 0.f;
    for (int j = lane; j < d; j += 64) {
        int s = col[start + j];
        ssum += __expf(lrelu(as_[s] + adi) - m);
    }
    #pragma unroll
    for (int off = 32; off; off >>= 1) ssum += __shfl_xor(ssum, off);
    float inv = 1.f / (ssum + 1e-16f);

    // pass C: weighted feature gather; lane = feature
    float acc = __expf(eself - m) * inv * h[wid * 64 + lane];
    for (int base = 0; base < d; base += 64) {
        int j = base + lane;
        float w = 0.f;
        int s = 0;
        if (j < d) {
            s = col[start + j];
            w = __expf(lrelu(as_[s] + adi) - m) * inv;
        }
        int cnt = min(64, d - base);
        for (int jj = 0; jj < cnt; jj++) {
            float wj = __shfl(w, jj);
            int sj = __shfl(s, jj);
            acc += wj * h[sj * 64 + lane];
        }
    }
    acc += bias[lane];
    out[wid * 64 + lane] = doElu ? eluf(acc) : acc;
}

// ---------------- Aggregation F=16: one wave per node, 4 edges x 16 feat ----------------

__global__ __launch_bounds__(256) void k_agg16(
    const int* __restrict__ rowptr, const int* __restrict__ deg,
    const int* __restrict__ col, const float* __restrict__ as_,
    const float* __restrict__ ad_, const float* __restrict__ h,
    const float* __restrict__ bias, float* __restrict__ out, int N)
{
    int wid = (blockIdx.x * blockDim.x + threadIdx.x) >> 6;
    int lane = threadIdx.x & 63;
    if (wid >= N) return;
    int f = lane & 15, eo = lane >> 4;
    int start = rowptr[wid];
    int d = deg[wid];
    float adi = ad_[wid];
    float asi = as_[wid];
    float eself = lrelu(asi + adi);

    float m = eself;
    for (int j = lane; j < d; j += 64) {
        int s = col[start + j];
        m = fmaxf(m, lrelu(as_[s] + adi));
    }
    #pragma unroll
    for (int off = 32; off; off >>= 1) m = fmaxf(m, __shfl_xor(m, off));

    float ssum = (lane == 0) ? __expf(eself - m) : 0.f;
    for (int j = lane; j < d; j += 64) {
        int s = col[start + j];
        ssum += __expf(lrelu(as_[s] + adi) - m);
    }
    #pragma unroll
    for (int off = 32; off; off >>= 1) ssum += __shfl_xor(ssum, off);
    float inv = 1.f / (ssum + 1e-16f);

    float acc = 0.f;
    if (eo == 0) acc = __expf(eself - m) * inv * h[wid * 16 + f];
    for (int j = eo; j < d; j += 4) {
        int s = col[start + j];
        float w = __expf(lrelu(as_[s] + adi) - m) * inv;
        acc += w * h[s * 16 + f];
    }
    acc += __shfl_xor(acc, 16);
    acc += __shfl_xor(acc, 32);
    if (lane < 16) out[wid * 16 + f] = acc + bias[f];
}

// ---------------- BatchNorm stats ----------------

__global__ __launch_bounds__(256) void k_bnstat(const float* __restrict__ logits,
                                                float* __restrict__ bn, int N) {
    int t = threadIdx.x;
    int c = t & 15;
    int g = (blockIdx.x * blockDim.x + t) >> 4;
    int stride = (gridDim.x * blockDim.x) >> 4;
    float s = 0.f, s2 = 0.f;
    for (int r = g; r < N; r += stride) {
        float v = logits[r * 16 + c];
        s += v;
        s2 += v * v;
    }
    s += __shfl_xor(s, 16);  s += __shfl_xor(s, 32);
    s2 += __shfl_xor(s2, 16); s2 += __shfl_xor(s2, 32);
    if ((t & 63) < 16) {
        atomicAdd(&bn[c], s);
        atomicAdd(&bn[16 + c], s2);
    }
}

// ---------------- BN apply + log_softmax + out (dtype-branched) ----------------

__global__ __launch_bounds__(256) void k_final(
    const float* __restrict__ logits, const float* __restrict__ bn,
    const float* __restrict__ gamma, const float* __restrict__ beta,
    const int* __restrict__ flag, void* __restrict__ out, int N)
{
    int r = blockIdx.x * blockDim.x + threadIdx.x;
    if (r >= N) return;
    int f = *flag;
    float invN = 1.f / (float)N;
    float y[16];
    float mx = -1e30f;
    #pragma unroll
    for (int c = 0; c < 16; c++) {
        float mu = bn[c] * invN;
        float var = bn[16 + c] * invN - mu * mu;
        float v = (logits[r * 16 + c] - mu) * rsqrtf(var + 1e-5f);
        v = v * gamma[c] + beta[c];
        y[c] = v;
        mx = fmaxf(mx, v);
    }
    float se = 0.f;
    #pragma unroll
    for (int c = 0; c < 16; c++) se += __expf(y[c] - mx);
    float lse = mx + __logf(se);
    #pragma unroll
    for (int c = 0; c < 16; c++) {
        float v = y[c] - lse;
        if (f) ((__hip_bfloat16*)out)[r * 16 + c] = __float2bfloat16(v);
        else   ((float*)out)[r * 16 + c] = v;
    }
}

// ---------------- launch ----------------

extern "C" void kernel_launch(void* const* d_in, const int* in_sizes, int n_in,
                              void* d_out, int out_size, void* d_ws, size_t ws_size,
                              hipStream_t stream) {
    const void* x1  = d_in[0];
    const void* x2  = d_in[1];
    const int*  ei1 = (const int*)d_in[2];
    const int*  ei2 = (const int*)d_in[3];

    const int N = in_sizes[0] / 64;
    const int E = in_sizes[2] / 2;

    char* p = (char*)d_ws;
    auto alloc = [&](size_t bytes) {
        void* q = (void*)p;
        p += (bytes + 255) & ~(size_t)255;
        return q;
    };
    float* h0      = (float*)alloc((size_t)N * 64 * 4);
    float* h1      = (float*)alloc((size_t)N * 64 * 4);
    float* hlin    = (float*)alloc((size_t)N * 64 * 4);
    float* as_     = (float*)alloc((size_t)N * 4);
    float* ad_     = (float*)alloc((size_t)N * 4);
    int* rowptr1   = (int*)alloc((size_t)N * 4);
    int* deg1      = (int*)alloc((size_t)N * 4);
    int* fill1     = (int*)alloc((size_t)N * 4);
    int* col1      = (int*)alloc((size_t)E * 4);   // reused as logits after layer 0
    int* rowptr2   = (int*)alloc((size_t)N * 4);
    int* deg2      = (int*)alloc((size_t)N * 4);
    int* fill2     = (int*)alloc((size_t)N * 4);
    int* col2      = (int*)alloc((size_t)E * 4);
    float* P       = (float*)alloc(P_TOTAL * 4);
    int* counters  = (int*)alloc(256);
    float* bn      = (float*)alloc(256);
    int* flag      = (int*)alloc(256);
    float* logits  = (float*)col1;                 // alias: col1 dead after layer-0 agg

    hipMemsetAsync(deg1, 0, (size_t)N * 4, stream);
    hipMemsetAsync(fill1, 0, (size_t)N * 4, stream);
    hipMemsetAsync(deg2, 0, (size_t)N * 4, stream);
    hipMemsetAsync(fill2, 0, (size_t)N * 4, stream);
    hipMemsetAsync(counters, 0, 256, stream);
    hipMemsetAsync(bn, 0, 256, stream);

    const int TB = 256;
    int gE = (E + TB - 1) / TB;
    int gN = (N + TB - 1) / TB;
    int gR16 = (N + 15) / 16;
    int gR64 = (N + 63) / 64;
    int gW = (N + 3) / 4;

    // dtype detect + param conversion
    k_detect<<<1, 64, 0, stream>>>((const unsigned int*)x1, flag);
    Ptrs14 pp;
    pp.p[0] = d_in[4];  pp.p[1] = d_in[8];  pp.p[2] = d_in[12];
    pp.p[3] = d_in[5];  pp.p[4] = d_in[6];  pp.p[5] = d_in[7];
    pp.p[6] = d_in[9];  pp.p[7] = d_in[10]; pp.p[8] = d_in[11];
    pp.p[9] = d_in[13]; pp.p[10] = d_in[14]; pp.p[11] = d_in[15];
    pp.p[12] = d_in[16]; pp.p[13] = d_in[17];
    k_params<<<14, 256, 0, stream>>>(pp, flag, P);

    // CSR for graph 1 and graph 2
    k_deg<<<gE, TB, 0, stream>>>(ei1 + E, E, deg1);
    k_alloc<<<gN, TB, 0, stream>>>(deg1, rowptr1, counters + 0, N);
    k_fill<<<gE, TB, 0, stream>>>(ei1, ei1 + E, E, rowptr1, fill1, col1);
    k_deg<<<gE, TB, 0, stream>>>(ei2 + E, E, deg2);
    k_alloc<<<gN, TB, 0, stream>>>(deg2, rowptr2, counters + 1, N);
    k_fill<<<gE, TB, 0, stream>>>(ei2, ei2 + E, E, rowptr2, fill2, col2);

    // Layer 0
    k_gemm_k64<<<gR16, TB, 0, stream>>>(x1, flag, P + P_W0, P + P_AS0, P + P_AD0,
                                        hlin, as_, ad_, N);
    k_agg64<<<gW, TB, 0, stream>>>(rowptr1, deg1, col1, as_, ad_, hlin, P + P_B0, h0, N, 1);
    // Layer 1
    k_gemm_k128<<<gR16, TB, 0, stream>>>(h0, x2, flag, P + P_W1, P + P_AS1, P + P_AD1,
                                         hlin, as_, ad_, N);
    k_agg64<<<gW, TB, 0, stream>>>(rowptr2, deg2, col2, as_, ad_, hlin, P + P_B1, h1, N, 1);
    // Layer 2
    k_gemm_k128_c16<<<gR64, TB, 0, stream>>>(h0, h1, P + P_W2, P + P_AS2, P + P_AD2,
                                             hlin, as_, ad_, N);
    k_agg16<<<gW, TB, 0, stream>>>(rowptr2, deg2, col2, as_, ad_, hlin, P + P_B2, logits, N);
    // BN + log_softmax
    k_bnstat<<<256, TB, 0, stream>>>(logits, bn, N);
    k_final<<<gN, TB, 0, stream>>>(logits, bn, P + P_GAMMA, P + P_BETA, flag,
                                   d_out, N);
}

// Round 4
// 869.581 us; speedup vs baseline: 1.1415x; 1.1415x over previous
//
#include <hip/hip_runtime.h>
#include <hip/hip_bf16.h>

#define DEV __device__ __forceinline__

DEV float bf2f(__hip_bfloat16 v) { return __bfloat162float(v); }
DEV float lrelu(float x) { return x > 0.f ? x : 0.2f * x; }
DEV float eluf(float x) { return x > 0.f ? x : (__expf(x) - 1.f); }

// Read element i of a float tensor that is either bf16 (f=1) or fp32 (f=0).
DEV float ldf(const void* p, int i, int f) {
    return f ? bf2f(((const __hip_bfloat16*)p)[i]) : ((const float*)p)[i];
}

// Inline dtype detection: if tensor data is bf16, the low 16 bits of words
// 0..63 are bf16 of ~N(0,1) -> exponent in [112,130] w.p. ~0.999; if fp32,
// they are uniform mantissa bits -> w.p. ~0.074. 64 samples => >10 sigma.
// Must be called with all lanes active (kernel top).
DEV int detect_bf16(const void* p) {
    const unsigned int* w = (const unsigned int*)p;
    unsigned int e = (w[threadIdx.x & 63] >> 7) & 0xFFu;
    int hit = (e >= 112u && e <= 130u) ? 1 : 0;
    unsigned long long b = __ballot(hit);
    return __popcll(b) > 32 ? 1 : 0;
}

// ---------------- param conversion (all small tensors -> fp32 P buffer) ----------------

struct Ptrs15 { const void* p[15]; };  // [14] = x1 (for detection)

#define P_W0 0
#define P_W1 4096
#define P_W2 12288
#define P_AS0 14336
#define P_AD0 14400
#define P_B0 14464
#define P_AS1 14528
#define P_AD1 14592
#define P_B1 14656
#define P_AS2 14720
#define P_AD2 14736
#define P_B2 14752
#define P_GAMMA 14768
#define P_BETA 14784
#define P_TOTAL 14800

__global__ void k_params(Ptrs15 pp, float* __restrict__ P) {
    const int narr[14] = {4096, 8192, 2048, 64, 64, 64, 64, 64, 64, 16, 16, 16, 16, 16};
    const int oarr[14] = {P_W0, P_W1, P_W2, P_AS0, P_AD0, P_B0, P_AS1, P_AD1, P_B1,
                          P_AS2, P_AD2, P_B2, P_GAMMA, P_BETA};
    int f = detect_bf16(pp.p[14]);
    int b = blockIdx.x;
    const void* src = pp.p[b];
    int nn = narr[b], oo = oarr[b];
    for (int i = threadIdx.x; i < nn; i += blockDim.x)
        P[oo + i] = ldf(src, i, f);
}

// ---------------- CSR build, both graphs ----------------

__global__ void k_deg2(const int* __restrict__ ei1, const int* __restrict__ ei2, int E,
                       int* __restrict__ deg1, int* __restrict__ deg2) {
    int i = blockIdx.x * blockDim.x + threadIdx.x;
    if (i < E) atomicAdd(&deg1[ei1[E + i]], 1);
    else if (i < 2 * E) atomicAdd(&deg2[ei2[i]], 1);  // ei2[E + (i-E)]
}

__global__ void k_alloc2(const int* __restrict__ deg1, int* __restrict__ rp1,
                         const int* __restrict__ deg2, int* __restrict__ rp2,
                         int* __restrict__ counters, int N) {
    int i = blockIdx.x * blockDim.x + threadIdx.x;
    if (i < N) rp1[i] = atomicAdd(&counters[0], deg1[i]);
    else if (i < 2 * N) rp2[i - N] = atomicAdd(&counters[1], deg2[i - N]);
}

__global__ void k_fill2(const int* __restrict__ ei1, const int* __restrict__ ei2, int E,
                        const int* __restrict__ rp1, int* __restrict__ fl1, int* __restrict__ c1,
                        const int* __restrict__ rp2, int* __restrict__ fl2, int* __restrict__ c2) {
    int i = blockIdx.x * blockDim.x + threadIdx.x;
    if (i < E) {
        int d = ei1[E + i];
        int p = rp1[d] + atomicAdd(&fl1[d], 1);
        c1[p] = ei1[i];
    } else if (i < 2 * E) {
        int j = i - E;
        int d = ei2[E + j];
        int p = rp2[d] + atomicAdd(&fl2[d], 1);
        c2[p] = ei2[j];
    }
}

// ---------------- persistent templated GEMM ----------------
// A = [A1(cols 0..63) | A2(cols 64..K-1)], K in {64,128}; C output cols.
// rawMask bit0/bit1: A1/A2 are dtype-branched inputs (else fp32 ws buffers).
// W staged to LDS once per block; xs k-major (conflict-free); fused a_src/a_dst dots.

template <int K, int C, int TR>
__global__ __launch_bounds__(256) void k_gemm(
    const void* __restrict__ A1, const void* __restrict__ A2, int rawMask,
    const float* __restrict__ W, const float* __restrict__ av, const float* __restrict__ dv,
    float* __restrict__ Hout, float* __restrict__ as_, float* __restrict__ ad_,
    int N, int numTiles)
{
    constexpr int CQ = C / 4;        // col groups of 4
    constexpr int RG = 256 / CQ;     // row groups
    constexpr int RPT = TR / RG;     // rows per thread
    constexpr int PADR = TR + 1;
    __shared__ float Ws[K * C];
    __shared__ float xs[K * PADR];

    int f = 0;
    if (rawMask) f = detect_bf16((rawMask & 1) ? A1 : A2);

    int t = threadIdx.x;
    for (int idx = t; idx < K * C; idx += 256) Ws[idx] = W[idx];

    const int cq = t % CQ, rg = t / CQ;

    for (int tile = blockIdx.x; tile < numTiles; tile += gridDim.x) {
        int rowBase = tile * TR;
        for (int idx = t; idx < K * TR; idx += 256) {
            int rr = idx / K, k = idx % K;
            int row = rowBase + rr;
            float v = 0.f;
            if (row < N) {
                if (k < 64) v = (rawMask & 1) ? ldf(A1, row * 64 + k, f)
                                              : ((const float*)A1)[row * 64 + k];
                else        v = (rawMask & 2) ? ldf(A2, row * 64 + (k - 64), f)
                                              : ((const float*)A2)[row * 64 + (k - 64)];
            }
            xs[k * PADR + rr] = v;
        }
        __syncthreads();

        float acc[RPT][4];
        #pragma unroll
        for (int r = 0; r < RPT; r++)
            for (int c = 0; c < 4; c++) acc[r][c] = 0.f;

        #pragma unroll 4
        for (int k = 0; k < K; k++) {
            float4 wv = *(const float4*)&Ws[k * C + cq * 4];
            #pragma unroll
            for (int r = 0; r < RPT; r++) {
                float xv = xs[k * PADR + rg * RPT + r];
                acc[r][0] += xv * wv.x;
                acc[r][1] += xv * wv.y;
                acc[r][2] += xv * wv.z;
                acc[r][3] += xv * wv.w;
            }
        }

        #pragma unroll
        for (int r = 0; r < RPT; r++) {
            int row = rowBase + rg * RPT + r;
            float4 o = {acc[r][0], acc[r][1], acc[r][2], acc[r][3]};
            float a0 = av[cq * 4], a1 = av[cq * 4 + 1], a2 = av[cq * 4 + 2], a3 = av[cq * 4 + 3];
            float d0 = dv[cq * 4], d1 = dv[cq * 4 + 1], d2 = dv[cq * 4 + 2], d3 = dv[cq * 4 + 3];
            float vs = o.x * a0 + o.y * a1 + o.z * a2 + o.w * a3;
            float vd = o.x * d0 + o.y * d1 + o.z * d2 + o.w * d3;
            #pragma unroll
            for (int off = CQ >> 1; off; off >>= 1) {
                vs += __shfl_xor(vs, off);
                vd += __shfl_xor(vd, off);
            }
            if (row < N) {
                *(float4*)&Hout[(size_t)row * C + cq * 4] = o;
                if (cq == 0) { as_[row] = vs; ad_[row] = vd; }
            }
        }
        __syncthreads();
    }
}

// ---------------- Aggregation F=64: one wave per node, fused softmax ----------------
// No max subtraction (softmax shift-invariant; |e| <= ~8 so fp32 exp is safe).
// Pass C: 16 lanes per row x 4 edge groups -> 4 rows (1KB) in flight per load.

__global__ __launch_bounds__(256) void k_agg64(
    const int* __restrict__ rowptr, const int* __restrict__ deg,
    const int* __restrict__ col, const float* __restrict__ as_,
    const float* __restrict__ ad_, const float* __restrict__ h,
    const float* __restrict__ bias, float* __restrict__ out,
    int N, int doElu)
{
    int wid = (blockIdx.x * blockDim.x + threadIdx.x) >> 6;
    int lane = threadIdx.x & 63;
    if (wid >= N) return;
    int start = rowptr[wid];
    int d = deg[wid];
    float adi = ad_[wid];
    float eself = __expf(lrelu(as_[wid] + adi));

    int dc = min(d, 64);
    float w = 0.f; int s = 0;
    if (lane < dc) { s = col[start + lane]; w = __expf(lrelu(as_[s] + adi)); }
    float ssum = w;
    for (int j = lane + 64; j < d; j += 64)
        ssum += __expf(lrelu(as_[col[start + j]] + adi));
    #pragma unroll
    for (int off = 32; off; off >>= 1) ssum += __shfl_xor(ssum, off);
    float inv = 1.f / (ssum + eself + 1e-16f);
    w *= inv;

    int fq = lane & 15, eg = lane >> 4;
    const float4* h4 = (const float4*)h;
    float4 acc = {0.f, 0.f, 0.f, 0.f};
    if (eg == 0) {
        float4 hv = h4[(size_t)wid * 16 + fq];
        float en = eself * inv;
        acc.x = en * hv.x; acc.y = en * hv.y; acc.z = en * hv.z; acc.w = en * hv.w;
    }
    {
        int iters = (dc + 3) >> 2;
        for (int it = 0; it < iters; it++) {
            int j = it * 4 + eg;
            float wj = __shfl(w, j);
            int sj = __shfl(s, j);
            if (j < dc) {
                float4 hv = h4[(size_t)sj * 16 + fq];
                acc.x += wj * hv.x; acc.y += wj * hv.y;
                acc.z += wj * hv.z; acc.w += wj * hv.w;
            }
        }
    }
    for (int base = 64; base < d; base += 64) {  // rare: degree > 64
        int cnt = min(64, d - base);
        float w2 = 0.f; int s2 = 0;
        if (lane < cnt) { s2 = col[start + base + lane]; w2 = __expf(lrelu(as_[s2] + adi)) * inv; }
        int iters = (cnt + 3) >> 2;
        for (int it = 0; it < iters; it++) {
            int j = it * 4 + eg;
            float wj = __shfl(w2, j);
            int sj = __shfl(s2, j);
            if (j < cnt) {
                float4 hv = h4[(size_t)sj * 16 + fq];
                acc.x += wj * hv.x; acc.y += wj * hv.y;
                acc.z += wj * hv.z; acc.w += wj * hv.w;
            }
        }
    }
    #pragma unroll
    for (int off = 16; off < 64; off <<= 1) {
        acc.x += __shfl_xor(acc.x, off);
        acc.y += __shfl_xor(acc.y, off);
        acc.z += __shfl_xor(acc.z, off);
        acc.w += __shfl_xor(acc.w, off);
    }
    if (lane < 16) {
        float4 b4 = ((const float4*)bias)[lane];
        float4 o = {acc.x + b4.x, acc.y + b4.y, acc.z + b4.z, acc.w + b4.w};
        if (doElu) { o.x = eluf(o.x); o.y = eluf(o.y); o.z = eluf(o.z); o.w = eluf(o.w); }
        ((float4*)out)[(size_t)wid * 16 + lane] = o;
    }
}

// ---------------- Aggregation F=16: 4 lanes per row x 16 edge groups ----------------

__global__ __launch_bounds__(256) void k_agg16(
    const int* __restrict__ rowptr, const int* __restrict__ deg,
    const int* __restrict__ col, const float* __restrict__ as_,
    const float* __restrict__ ad_, const float* __restrict__ h,
    const float* __restrict__ bias, float* __restrict__ out, int N)
{
    int wid = (blockIdx.x * blockDim.x + threadIdx.x) >> 6;
    int lane = threadIdx.x & 63;
    if (wid >= N) return;
    int start = rowptr[wid];
    int d = deg[wid];
    float adi = ad_[wid];
    float eself = __expf(lrelu(as_[wid] + adi));

    int dc = min(d, 64);
    float w = 0.f; int s = 0;
    if (lane < dc) { s = col[start + lane]; w = __expf(lrelu(as_[s] + adi)); }
    float ssum = w;
    for (int j = lane + 64; j < d; j += 64)
        ssum += __expf(lrelu(as_[col[start + j]] + adi));
    #pragma unroll
    for (int off = 32; off; off >>= 1) ssum += __shfl_xor(ssum, off);
    float inv = 1.f / (ssum + eself + 1e-16f);
    w *= inv;

    int fq = lane & 3, eg = lane >> 2;
    const float4* h4 = (const float4*)h;
    float4 acc = {0.f, 0.f, 0.f, 0.f};
    if (eg == 0) {
        float4 hv = h4[(size_t)wid * 4 + fq];
        float en = eself * inv;
        acc.x = en * hv.x; acc.y = en * hv.y; acc.z = en * hv.z; acc.w = en * hv.w;
    }
    {
        int iters = (dc + 15) >> 4;
        for (int it = 0; it < iters; it++) {
            int j = it * 16 + eg;
            float wj = __shfl(w, j);
            int sj = __shfl(s, j);
            if (j < dc) {
                float4 hv = h4[(size_t)sj * 4 + fq];
                acc.x += wj * hv.x; acc.y += wj * hv.y;
                acc.z += wj * hv.z; acc.w += wj * hv.w;
            }
        }
    }
    for (int base = 64; base < d; base += 64) {
        int cnt = min(64, d - base);
        float w2 = 0.f; int s2 = 0;
        if (lane < cnt) { s2 = col[start + base + lane]; w2 = __expf(lrelu(as_[s2] + adi)) * inv; }
        int iters = (cnt + 15) >> 4;
        for (int it = 0; it < iters; it++) {
            int j = it * 16 + eg;
            float wj = __shfl(w2, j);
            int sj = __shfl(s2, j);
            if (j < cnt) {
                float4 hv = h4[(size_t)sj * 4 + fq];
                acc.x += wj * hv.x; acc.y += wj * hv.y;
                acc.z += wj * hv.z; acc.w += wj * hv.w;
            }
        }
    }
    #pragma unroll
    for (int off = 4; off < 64; off <<= 1) {
        acc.x += __shfl_xor(acc.x, off);
        acc.y += __shfl_xor(acc.y, off);
        acc.z += __shfl_xor(acc.z, off);
        acc.w += __shfl_xor(acc.w, off);
    }
    if (lane < 4) {
        float4 b4 = ((const float4*)bias)[lane];
        float4 o = {acc.x + b4.x, acc.y + b4.y, acc.z + b4.z, acc.w + b4.w};
        ((float4*)out)[(size_t)wid * 4 + lane] = o;
    }
}

// ---------------- BatchNorm stats ----------------

__global__ __launch_bounds__(256) void k_bnstat(const float* __restrict__ logits,
                                                float* __restrict__ bn, int N) {
    int t = threadIdx.x;
    int c = t & 15;
    int g = (blockIdx.x * blockDim.x + t) >> 4;
    int stride = (gridDim.x * blockDim.x) >> 4;
    float s = 0.f, s2 = 0.f;
    for (int r = g; r < N; r += stride) {
        float v = logits[r * 16 + c];
        s += v;
        s2 += v * v;
    }
    s += __shfl_xor(s, 16);  s += __shfl_xor(s, 32);
    s2 += __shfl_xor(s2, 16); s2 += __shfl_xor(s2, 32);
    if ((t & 63) < 16) {
        atomicAdd(&bn[c], s);
        atomicAdd(&bn[16 + c], s2);
    }
}

// ---------------- BN apply + log_softmax + out (dtype-branched) ----------------

__global__ __launch_bounds__(256) void k_final(
    const float* __restrict__ logits, const float* __restrict__ bn,
    const float* __restrict__ gamma, const float* __restrict__ beta,
    const void* __restrict__ x1, void* __restrict__ out, int N)
{
    int f = detect_bf16(x1);
    int r = blockIdx.x * blockDim.x + threadIdx.x;
    if (r >= N) return;
    float invN = 1.f / (float)N;
    float y[16];
    float mx = -1e30f;
    #pragma unroll
    for (int c = 0; c < 16; c++) {
        float mu = bn[c] * invN;
        float var = bn[16 + c] * invN - mu * mu;
        float v = (logits[r * 16 + c] - mu) * rsqrtf(var + 1e-5f);
        v = v * gamma[c] + beta[c];
        y[c] = v;
        mx = fmaxf(mx, v);
    }
    float se = 0.f;
    #pragma unroll
    for (int c = 0; c < 16; c++) se += __expf(y[c] - mx);
    float lse = mx + __logf(se);
    #pragma unroll
    for (int c = 0; c < 16; c++) {
        float v = y[c] - lse;
        if (f) ((__hip_bfloat16*)out)[r * 16 + c] = __float2bfloat16(v);
        else   ((float*)out)[r * 16 + c] = v;
    }
}

// ---------------- launch ----------------

extern "C" void kernel_launch(void* const* d_in, const int* in_sizes, int n_in,
                              void* d_out, int out_size, void* d_ws, size_t ws_size,
                              hipStream_t stream) {
    const void* x1  = d_in[0];
    const void* x2  = d_in[1];
    const int*  ei1 = (const int*)d_in[2];
    const int*  ei2 = (const int*)d_in[3];

    const int N = in_sizes[0] / 64;
    const int E = in_sizes[2] / 2;

    char* p = (char*)d_ws;
    auto alloc = [&](size_t bytes) {
        void* q = (void*)p;
        p += (bytes + 255) & ~(size_t)255;
        return q;
    };
    // zero region: deg1, fill1, deg2, fill2, counters+bn  (single memset)
    char* zbase    = (char*)alloc(0);
    int* deg1      = (int*)alloc((size_t)N * 4);
    int* fill1     = (int*)alloc((size_t)N * 4);
    int* deg2      = (int*)alloc((size_t)N * 4);
    int* fill2     = (int*)alloc((size_t)N * 4);
    int* counters  = (int*)alloc(256);   // [0],[1] = bucket counters
    float* bn      = (float*)alloc(256); // [0..15]=sum, [16..31]=sumsq
    size_t zbytes  = (size_t)((char*)alloc(0) - zbase);

    float* h0      = (float*)alloc((size_t)N * 64 * 4);
    float* h1      = (float*)alloc((size_t)N * 64 * 4);
    float* hlin    = (float*)alloc((size_t)N * 64 * 4);
    float* as_     = (float*)alloc((size_t)N * 4);
    float* ad_     = (float*)alloc((size_t)N * 4);
    int* rowptr1   = (int*)alloc((size_t)N * 4);
    int* col1      = (int*)alloc((size_t)E * 4);   // aliased as logits after layer-0 agg
    int* rowptr2   = (int*)alloc((size_t)N * 4);
    int* col2      = (int*)alloc((size_t)E * 4);
    float* P       = (float*)alloc(P_TOTAL * 4);
    float* logits  = (float*)col1;

    hipMemsetAsync(zbase, 0, zbytes, stream);

    const int TB = 256;
    int gE2 = (2 * E + TB - 1) / TB;
    int gN  = (N + TB - 1) / TB;
    int gN2 = (2 * N + TB - 1) / TB;
    int gW  = (N + 3) / 4;

    Ptrs15 pp;
    pp.p[0] = d_in[4];  pp.p[1] = d_in[8];   pp.p[2] = d_in[12];
    pp.p[3] = d_in[5];  pp.p[4] = d_in[6];   pp.p[5] = d_in[7];
    pp.p[6] = d_in[9];  pp.p[7] = d_in[10];  pp.p[8] = d_in[11];
    pp.p[9] = d_in[13]; pp.p[10] = d_in[14]; pp.p[11] = d_in[15];
    pp.p[12] = d_in[16]; pp.p[13] = d_in[17]; pp.p[14] = x1;
    k_params<<<14, 256, 0, stream>>>(pp, P);

    k_deg2<<<gE2, TB, 0, stream>>>(ei1, ei2, E, deg1, deg2);
    k_alloc2<<<gN2, TB, 0, stream>>>(deg1, rowptr1, deg2, rowptr2, counters, N);
    k_fill2<<<gE2, TB, 0, stream>>>(ei1, ei2, E, rowptr1, fill1, col1,
                                    rowptr2, fill2, col2);

    // Layer 0: x1 (raw) @ W0 -> hlin; aggregate graph1 -> h0 (elu)
    {
        int nt = (N + 63) / 64;
        k_gemm<64, 64, 64><<<(nt < 512 ? nt : 512), TB, 0, stream>>>(
            x1, x1, 1, P + P_W0, P + P_AS0, P + P_AD0, hlin, as_, ad_, N, nt);
    }
    k_agg64<<<gW, TB, 0, stream>>>(rowptr1, deg1, col1, as_, ad_, hlin, P + P_B0, h0, N, 1);

    // Layer 1: [h0 | x2(raw)] @ W1 -> hlin; aggregate graph2 -> h1 (elu)
    {
        int nt = (N + 31) / 32;
        k_gemm<128, 64, 32><<<(nt < 512 ? nt : 512), TB, 0, stream>>>(
            h0, x2, 2, P + P_W1, P + P_AS1, P + P_AD1, hlin, as_, ad_, N, nt);
    }
    k_agg64<<<gW, TB, 0, stream>>>(rowptr2, deg2, col2, as_, ad_, hlin, P + P_B1, h1, N, 1);

    // Layer 2: [h0 | h1] @ W2 -> hlin(:,:16); aggregate graph2 -> logits
    {
        int nt = (N + 63) / 64;
        k_gemm<128, 16, 64><<<(nt < 512 ? nt : 512), TB, 0, stream>>>(
            h0, h1, 0, P + P_W2, P + P_AS2, P + P_AD2, hlin, as_, ad_, N, nt);
    }
    k_agg16<<<gW, TB, 0, stream>>>(rowptr2, deg2, col2, as_, ad_, hlin, P + P_B2, logits, N);

    // BN + log_softmax
    k_bnstat<<<256, TB, 0, stream>>>(logits, bn, N);
    k_final<<<gN, TB, 0, stream>>>(logits, bn, P + P_GAMMA, P + P_BETA, x1, d_out, N);
}